// Round 10
// baseline (189.845 us; speedup 1.0000x reference)
//
#include <hip/hip_runtime.h>
#include <math.h>

#define NV 16385
#define NEG -1e30f
#define SCALE 2.8853900817779268f  // 2*log2(e): tanh(x) = 1 - 2/(exp2(SCALE*x)+1)

typedef __attribute__((ext_vector_type(8))) short short8;
typedef __attribute__((ext_vector_type(8))) unsigned short ushort8;
typedef __attribute__((ext_vector_type(4))) float f32x4;

// Device-global scratch. g_gold reset by k_tail each launch (.bss-zero on first).
__device__ float g_mats[512 * 64];  // one 8x8 chunk matrix per block (row-major)
__device__ float g_gold;            // gold-path sum

__device__ __forceinline__ unsigned short f2bf(float x) {
  union { float f; unsigned int u; } c; c.f = x;
  unsigned int u = c.u;
  unsigned int r = (u + 0x7fffu + ((u >> 16) & 1u)) >> 16;  // RNE
  return (unsigned short)r;
}
__device__ __forceinline__ float bf2f(unsigned short u) {
  union { unsigned int u; float f; } c; c.u = ((unsigned int)u) << 16;
  return c.f;
}

__device__ __forceinline__ float lse8(float x0, float x1, float x2, float x3,
                                      float x4, float x5, float x6, float x7) {
  float m = fmaxf(fmaxf(fmaxf(x0, x1), fmaxf(x2, x3)),
                  fmaxf(fmaxf(x4, x5), fmaxf(x6, x7)));
  float s = __expf(x0 - m) + __expf(x1 - m) + __expf(x2 - m) + __expf(x3 - m) +
            __expf(x4 - m) + __expf(x5 - m) + __expf(x6 - m) + __expf(x7 - m);
  return m + __logf(s);
}

// Full-wave 8x8 log-semiring matmul: lane l=(i*8+j) holds A[i][j], B[i][j];
// returns (A (X) B)[i][j] = lse_k(A[i][k] + B[k][j]).  A = later chunk.
__device__ __forceinline__ float comb8(float A, float B, int i8, int j) {
  float x0 = __shfl(A, i8 + 0) + __shfl(B, 0 + j);
  float x1 = __shfl(A, i8 + 1) + __shfl(B, 8 + j);
  float x2 = __shfl(A, i8 + 2) + __shfl(B, 16 + j);
  float x3 = __shfl(A, i8 + 3) + __shfl(B, 24 + j);
  float x4 = __shfl(A, i8 + 4) + __shfl(B, 32 + j);
  float x5 = __shfl(A, i8 + 5) + __shfl(B, 40 + j);
  float x6 = __shfl(A, i8 + 6) + __shfl(B, 48 + j);
  float x7 = __shfl(A, i8 + 7) + __shfl(B, 56 + j);
  return lse8(x0, x1, x2, x3, x4, x5, x6, x7);
}

// Self-contained chunk kernel. Grid 512 blocks x 256 thr.
// Block y: nodes i in [i0+1, i0+32], i0 = y*32; ALL 256 hidden units in 4 rounds.
// Round hx: MFMA A[p][h]=emb[p]@W1_top, B[i][h]=emb[i]@W1_bot for h-tile ->
// LDS (bf16, pre-scaled by 2*log2e, b1 folded into A) -> per-edge partial
// accumulate (1 edge/thread). Epilogue: softplus -> 32-step chunk recurrence
// (8 lanes) -> one 8x8 matrix. No g_part, no fences.
__global__ __launch_bounds__(256, 4) void k12(const float* __restrict__ emb,
                                              const float* __restrict__ W1,
                                              const float* __restrict__ b1,
                                              const float* __restrict__ W2,
                                              const float* __restrict__ b2) {
  __shared__ __align__(16) unsigned short lds[13128];  // 26.3 KB
  unsigned short* Es  = lds;                   // [48][136] emb tile (rows i0-7..i0+40)
  unsigned short* CA  = lds + 6528;            // [48][72]  A-part C tile (rows 39+ pad)
  unsigned short* CB  = lds + 9984;            // [32][72]  B-part C tile
  unsigned short* W2s = lds + 12288;           // [256] bf16(-2*W2), all h
  float* Wsum  = (float*)(lds + 12544);        // [32] per-granule sum of W2
  float* wf    = (float*)(lds + 12608);        // [32][8] chunk d-values
  float* l2red = (float*)(lds + 13120);        // [4] gold wave partials

  const int t = threadIdx.x;
  const int i0 = blockIdx.x << 5;
  const int wv = t >> 6, lane = t & 63;
  const int l15 = lane & 15, quad = lane >> 4;
  const float b2v = b2[0];

  W2s[t] = f2bf(-2.f * W2[t]);
  if (t < 32) {
    float s = 0.f;
#pragma unroll
    for (int jj = 0; jj < 8; ++jj) s += W2[(t << 3) + jj];
    Wsum[t] = s;
  }
  // Stage emb rows [i0-7, i0+41) x all 128 k -> bf16. 48 rows x 32 float4 = 1536.
#pragma unroll
  for (int it = 0; it < 6; ++it) {
    int idx = t + (it << 8);
    int row = idx >> 5;             // 0..47
    int k4 = (idx & 31) << 2;
    int v = i0 - 7 + row;
    float4 g = make_float4(0.f, 0.f, 0.f, 0.f);
    if (v >= 0 && v < NV) g = *(const float4*)&emb[v * 128 + k4];
    uint2 pk;
    pk.x = f2bf(g.x) | ((unsigned int)f2bf(g.y) << 16);
    pk.y = f2bf(g.z) | ((unsigned int)f2bf(g.w) << 16);
    *(uint2*)&Es[row * 136 + k4] = pk;
  }

  const int k = t & 7, q = t >> 3;  // this thread's edge: node i0+1+q, pred offset k
  float part = 0.f;
  for (int hx = 0; hx < 4; ++hx) {
    const int h0 = hx << 6;
    const int colh = h0 + (wv << 4) + l15;  // this lane's W1 column
    __syncthreads();  // hx=0: staging done; hx>0: prev edge reads done
    // W1 fragments straight from global (L2-hot): k = kc*32 + quad*8 + i.
    short8 fA[4], fB[4];
#pragma unroll
    for (int kc = 0; kc < 4; ++kc) {
      const int kb = (kc << 5) + (quad << 3);
#pragma unroll
      for (int i = 0; i < 8; i += 2) {
        float a0 = W1[(kb + i) * 256 + colh];
        float a1 = W1[(kb + i + 1) * 256 + colh];
        float c0 = W1[(128 + kb + i) * 256 + colh];
        float c1 = W1[(128 + kb + i + 1) * 256 + colh];
        ((unsigned int*)&fA[kc])[i >> 1] = f2bf(a0) | ((unsigned int)f2bf(a1) << 16);
        ((unsigned int*)&fB[kc])[i >> 1] = f2bf(c0) | ((unsigned int)f2bf(c1) << 16);
      }
    }
    f32x4 accA[3], accB[2];
#pragma unroll
    for (int m = 0; m < 3; ++m) accA[m] = (f32x4){0.f, 0.f, 0.f, 0.f};
#pragma unroll
    for (int m = 0; m < 2; ++m) accB[m] = (f32x4){0.f, 0.f, 0.f, 0.f};
#pragma unroll
    for (int kc = 0; kc < 4; ++kc) {
      const int kbase = (kc << 5) + (quad << 3);
#pragma unroll
      for (int mf = 0; mf < 3; ++mf) {
        short8 a = *(const short8*)&Es[((mf << 4) + l15) * 136 + kbase];
        accA[mf] = __builtin_amdgcn_mfma_f32_16x16x32_bf16(a, fA[kc], accA[mf], 0, 0, 0);
      }
#pragma unroll
      for (int mf = 0; mf < 2; ++mf) {
        short8 a = *(const short8*)&Es[(8 + (mf << 4) + l15) * 136 + kbase];
        accB[mf] = __builtin_amdgcn_mfma_f32_16x16x32_bf16(a, fB[kc], accB[mf], 0, 0, 0);
      }
    }
    // C store (bf16, pre-scaled). C/D frag: row = quad*4+reg, col = lane&15.
    const int hcol = (wv << 4) + l15;
    const float b1s = b1[colh];
#pragma unroll
    for (int mf = 0; mf < 3; ++mf) {
      int rb = (mf << 4) + (quad << 2);
#pragma unroll
      for (int rr = 0; rr < 4; ++rr)
        CA[(rb + rr) * 72 + hcol] = f2bf((accA[mf][rr] + b1s) * SCALE);
    }
#pragma unroll
    for (int mf = 0; mf < 2; ++mf) {
      int rb = (mf << 4) + (quad << 2);
#pragma unroll
      for (int rr = 0; rr < 4; ++rr)
        CB[(rb + rr) * 72 + hcol] = f2bf(accB[mf][rr] * SCALE);
    }
    __syncthreads();
    // Edge phase: accumulate this round's 64 h into part.
#pragma unroll
    for (int g = 0; g < 8; ++g) {
      const int s = (g + (k << 1)) & 7;  // granule rotation: conflict-uniform banks
      ushort8 wv8 = *(const ushort8*)&W2s[h0 + (s << 3)];
      float m2w[8];
#pragma unroll
      for (int jj = 0; jj < 8; ++jj) m2w[jj] = bf2f(wv8[jj]);
      const float ws = Wsum[(hx << 3) + s];
      ushort8 a8 = *(const ushort8*)&CA[(7 + q - k) * 72 + (s << 3)];
      ushort8 b8 = *(const ushort8*)&CB[q * 72 + (s << 3)];
      float p = part;
#pragma unroll
      for (int jj = 0; jj < 8; ++jj) {
        float x = bf2f(a8[jj]) + bf2f(b8[jj]);
        float e = __builtin_amdgcn_exp2f(x);
        float r = __builtin_amdgcn_rcpf(e + 1.f);
        p = fmaf(r, m2w[jj], p);  // p += -2*W2*rcp(exp2(x)+1)
      }
      part = p + ws;  // + sum W2 (tanh fold)
    }
  }
  // Epilogue: softplus, mask, chunk recurrence.
  float d = part + b2v;
  d = fmaxf(d, 0.f) + log1pf(__expf(-fabsf(d)));
  if (blockIdx.x == 0 && k > q) d = 1e30f;  // node q+1 has valid preds k <= q only
  wf[(q << 3) + k] = d;
  float gd = (k == 0) ? d : 0.f;  // gold-path edges
#pragma unroll
  for (int off = 32; off > 0; off >>= 1) gd += __shfl_xor(gd, off, 64);
  if (lane == 0) l2red[wv] = gd;
  __syncthreads();
  if (t == 0) atomicAdd(&g_gold, l2red[0] + l2red[1] + l2red[2] + l2red[3]);
  if (t < 8) {  // lanes 0-7: 32-step recurrence, lane j owns column j
    const int j = t;
    float P[8];
#pragma unroll
    for (int kk = 0; kk < 8; ++kk) P[kk] = (kk == j) ? 0.f : NEG;
    for (int s = 0; s < 32; ++s) {
      const float* wp = &wf[s << 3];
      float4 wa = *(const float4*)wp;
      float4 wb = *(const float4*)(wp + 4);
      float nv = lse8(P[0] - wa.x, P[1] - wa.y, P[2] - wa.z, P[3] - wa.w,
                      P[4] - wb.x, P[5] - wb.y, P[6] - wb.z, P[7] - wb.w);
#pragma unroll
      for (int kk = 7; kk > 0; --kk) P[kk] = P[kk - 1];
      P[0] = nv;
    }
#pragma unroll
    for (int kk = 0; kk < 8; ++kk)
      g_mats[(blockIdx.x << 6) + (kk << 3) + j] = P[kk];  // row-major
  }
}

// K_tail: ONE block, 256 thr. Wave w combines mats [128w, 128w+128) sequentially
// (ascending node order, later chunk on the left), then wave partials combine.
__global__ __launch_bounds__(256) void k_tail(float* __restrict__ out) {
  __shared__ float l2m[4][64];
  const int t = threadIdx.x, l = t & 63, w = t >> 6;
  const int i8 = (l >> 3) << 3, j = l & 7;
  const int m0 = w << 7;
  float R = g_mats[(m0 << 6) + l];
  float nxt = g_mats[((m0 + 1) << 6) + l];
  for (int m = 1; m < 128; ++m) {
    float cur = nxt;
    if (m + 1 < 128) nxt = g_mats[((m0 + m + 1) << 6) + l];  // prefetch
    R = comb8(cur, R, i8, j);
  }
  l2m[w][l] = R;
  __syncthreads();
  if (t < 64) {
    float G = l2m[0][t];
    G = comb8(l2m[1][t], G, i8, j);
    G = comb8(l2m[2][t], G, i8, j);
    G = comb8(l2m[3][t], G, i8, j);
    if (t == 0) {
      out[0] = g_gold + G;  // gold + (prod)[0][0]
      g_gold = 0.f;         // reset for next launch / graph replay
    }
  }
}

extern "C" void kernel_launch(void* const* d_in, const int* in_sizes, int n_in,
                              void* d_out, int out_size, void* d_ws, size_t ws_size,
                              hipStream_t stream) {
  const float* emb = (const float*)d_in[0];
  const float* W1 = (const float*)d_in[1];
  const float* b1 = (const float*)d_in[2];
  const float* W2 = (const float*)d_in[3];
  const float* b2 = (const float*)d_in[4];
  float* out = (float*)d_out;
  hipLaunchKernelGGL(k12, dim3(512), dim3(256), 0, stream, emb, W1, b1, W2, b2);
  hipLaunchKernelGGL(k_tail, dim3(1), dim3(256), 0, stream, out);
}

// Round 11
// 112.182 us; speedup vs baseline: 1.6923x; 1.6923x over previous
//
#include <hip/hip_runtime.h>
#include <math.h>

#define NV 16385
#define NEDGE 131072
#define NEG -1e30f
#define SCALE 2.8853900817779268f  // 2*log2(e): tanh(x) = 1 - 2/(exp2(SCALE*x)+1)

typedef __attribute__((ext_vector_type(8))) short short8;
typedef __attribute__((ext_vector_type(4))) float f32x4;

// Scratch as static device globals. g_gold/g_done reset by the final tail block
// each launch (.bss-zero on first launch) -> graph replays identical.
__device__ float g_part[4 * NEDGE];  // per-h-tile partial edge sums
__device__ float g_mats[32 * 64];    // 32 segment matrices (8x8, row-major)
__device__ float g_gold;             // gold-path sum
__device__ int g_done;               // segment-done counter

__device__ __forceinline__ unsigned short f2bf(float x) {
  union { float f; unsigned int u; } c; c.f = x;
  unsigned int u = c.u;
  unsigned int r = (u + 0x7fffu + ((u >> 16) & 1u)) >> 16;  // RNE
  return (unsigned short)r;
}

__device__ __forceinline__ float lse8(float x0, float x1, float x2, float x3,
                                      float x4, float x5, float x6, float x7) {
  float m = fmaxf(fmaxf(fmaxf(x0, x1), fmaxf(x2, x3)),
                  fmaxf(fmaxf(x4, x5), fmaxf(x6, x7)));
  float s = __expf(x0 - m) + __expf(x1 - m) + __expf(x2 - m) + __expf(x3 - m) +
            __expf(x4 - m) + __expf(x5 - m) + __expf(x6 - m) + __expf(x7 - m);
  return m + __logf(s);
}

// Full-wave 8x8 log-semiring matmul: lane l=(i*8+j) holds A[i][j], B[i][j];
// returns (A (X) B)[i][j] = lse_k(A[i][k] + B[k][j]).  A = later chunk.
__device__ __forceinline__ float comb8(float A, float B, int i8, int j) {
  float x0 = __shfl(A, i8 + 0) + __shfl(B, 0 + j);
  float x1 = __shfl(A, i8 + 1) + __shfl(B, 8 + j);
  float x2 = __shfl(A, i8 + 2) + __shfl(B, 16 + j);
  float x3 = __shfl(A, i8 + 3) + __shfl(B, 24 + j);
  float x4 = __shfl(A, i8 + 4) + __shfl(B, 32 + j);
  float x5 = __shfl(A, i8 + 5) + __shfl(B, 40 + j);
  float x6 = __shfl(A, i8 + 6) + __shfl(B, 48 + j);
  float x7 = __shfl(A, i8 + 7) + __shfl(B, 56 + j);
  return lse8(x0, x1, x2, x3, x4, x5, x6, x7);
}

// One edge-phase term: acc += w * rcp(exp2(x)+1)   (x pre-scaled by 2*log2e)
#define ETERM(x, w, acc)                                   \
  {                                                        \
    float e_ = __builtin_amdgcn_exp2f(x);                  \
    acc = fmaf(__builtin_amdgcn_rcpf(e_ + 1.f), (w), acc); \
  }

// Fused projection + edge kernel. Grid (4 h-tiles, 256 node-tiles of 64), 256 thr.
// vs R8/R9: C tiles + W2 kept fp32 in LDS (no bf16 pack/unpack on the edge path),
// 4 independent edge accumulators (ILP), W1 frags direct from global (L2-hot).
__global__ __launch_bounds__(256, 4) void k12_fused(const float* __restrict__ emb,
                                                    const float* __restrict__ W1,
                                                    const float* __restrict__ b1,
                                                    const float* __restrict__ W2) {
  __shared__ __align__(16) unsigned short lds[19728];  // 38.5 KB
  unsigned short* Es = lds;               // [80][136] u16 emb tile (phase 1)
  float* CA  = (float*)lds;               // [80][68] f32 (aliases Es, phase 2)
  float* CB  = (float*)(lds + 10880);     // [64][68] f32 (byte 21760)
  float* W2s = (float*)(lds + 19584);     // [64] f32 (-2*W2)       (byte 39168)
  float* Wsum = (float*)(lds + 19712);    // [8] per-granule sum    (byte 39424)

  const int t = threadIdx.x;
  const int h0 = blockIdx.x << 6;
  const int i0 = blockIdx.y << 6;
  const int wv = t >> 6, lane = t & 63;
  const int l15 = lane & 15, quad = lane >> 4;
  const int colh = h0 + (wv << 4) + l15;  // this lane's W1 column / C column

  if (t < 64) W2s[t] = -2.f * W2[h0 + t];
  if (t < 8) {
    float s = 0.f;
#pragma unroll
    for (int jj = 0; jj < 8; ++jj) s += W2[h0 + (t << 3) + jj];
    Wsum[t] = s;
  }

  // Stage emb rows [i0-7, i0+73) x all 128 k -> bf16. 80 rows x 32 float4 = 2560.
#pragma unroll
  for (int it = 0; it < 10; ++it) {
    int idx = t + (it << 8);
    int row = idx >> 5;
    int k4 = (idx & 31) << 2;
    int v = i0 - 7 + row;
    float4 g = make_float4(0.f, 0.f, 0.f, 0.f);
    if (v >= 0 && v < NV) g = *(const float4*)&emb[v * 128 + k4];
    uint2 pk;
    pk.x = f2bf(g.x) | ((unsigned int)f2bf(g.y) << 16);
    pk.y = f2bf(g.z) | ((unsigned int)f2bf(g.w) << 16);
    *(uint2*)&Es[row * 136 + k4] = pk;
  }

  f32x4 accA[5], accB[4];
#pragma unroll
  for (int m = 0; m < 5; ++m) accA[m] = (f32x4){0.f, 0.f, 0.f, 0.f};
#pragma unroll
  for (int m = 0; m < 4; ++m) accB[m] = (f32x4){0.f, 0.f, 0.f, 0.f};

  // W1 fragments straight from global (L2-hot): frag kc -> k = kc*32 + quad*8 + i.
  short8 fA[4], fB[4];
#pragma unroll
  for (int kc = 0; kc < 4; ++kc) {
    const int kb = (kc << 5) + (quad << 3);
#pragma unroll
    for (int i = 0; i < 8; i += 2) {
      float a0 = W1[(kb + i) * 256 + colh];
      float a1 = W1[(kb + i + 1) * 256 + colh];
      float c0 = W1[(128 + kb + i) * 256 + colh];
      float c1 = W1[(128 + kb + i + 1) * 256 + colh];
      ((unsigned int*)&fA[kc])[i >> 1] = f2bf(a0) | ((unsigned int)f2bf(a1) << 16);
      ((unsigned int*)&fB[kc])[i >> 1] = f2bf(c0) | ((unsigned int)f2bf(c1) << 16);
    }
  }
  __syncthreads();

#pragma unroll
  for (int kc = 0; kc < 4; ++kc) {
    const int kbase = (kc << 5) + (quad << 3);
#pragma unroll
    for (int mf = 0; mf < 5; ++mf) {
      short8 a = *(const short8*)&Es[((mf << 4) + l15) * 136 + kbase];
      accA[mf] = __builtin_amdgcn_mfma_f32_16x16x32_bf16(a, fA[kc], accA[mf], 0, 0, 0);
    }
#pragma unroll
    for (int mf = 0; mf < 4; ++mf) {
      short8 a = *(const short8*)&Es[(8 + (mf << 4) + l15) * 136 + kbase];
      accB[mf] = __builtin_amdgcn_mfma_f32_16x16x32_bf16(a, fB[kc], accB[mf], 0, 0, 0);
    }
  }
  __syncthreads();  // all MFMA reads of Es done before aliasing C over it
  // Store C tiles fp32 (pre-scaled by 2*log2e; b1 folded into A).
  // C/D frag: row = quad*4+reg, col = lane&15.  Pitch 68: store conflicts 2-way (free).
  const int hcol = (wv << 4) + l15;
  const float b1s = b1[h0 + hcol];
#pragma unroll
  for (int mf = 0; mf < 5; ++mf) {
    int rb = (mf << 4) + (quad << 2);
#pragma unroll
    for (int rr = 0; rr < 4; ++rr)
      CA[(rb + rr) * 68 + hcol] = (accA[mf][rr] + b1s) * SCALE;
  }
#pragma unroll
  for (int mf = 0; mf < 4; ++mf) {
    int rb = (mf << 4) + (quad << 2);
#pragma unroll
    for (int rr = 0; rr < 4; ++rr)
      CB[(rb + rr) * 68 + hcol] = accB[mf][rr] * SCALE;
  }
  __syncthreads();
  // Edge phase: thread t -> k = t&7, qb = t>>3; edges q = qb, qb+32.
  // 4 independent accumulators; Wsum folded once at the end.
  const int k = t & 7;
  const int qb = t >> 3;
  float ws_all = 0.f;
#pragma unroll
  for (int s = 0; s < 8; ++s) ws_all += Wsum[s];
  float pa0 = 0.f, pa1 = 0.f, pb0 = 0.f, pb1 = 0.f;
#pragma unroll
  for (int g = 0; g < 8; ++g) {
    const int s = (g + (k << 1)) & 7;  // granule rotation: conflict-uniform banks
    const float* wp = &W2s[s << 3];
    float4 w0 = *(const float4*)wp;
    float4 w1 = *(const float4*)(wp + 4);
    {
      const float* ap = &CA[(7 + qb - k) * 68 + (s << 3)];
      const float* bp = &CB[qb * 68 + (s << 3)];
      float4 a0 = *(const float4*)ap, a1 = *(const float4*)(ap + 4);
      float4 b0 = *(const float4*)bp, b1v = *(const float4*)(bp + 4);
      ETERM(a0.x + b0.x, w0.x, pa0); ETERM(a0.y + b0.y, w0.y, pa0);
      ETERM(a0.z + b0.z, w0.z, pa0); ETERM(a0.w + b0.w, w0.w, pa0);
      ETERM(a1.x + b1v.x, w1.x, pa1); ETERM(a1.y + b1v.y, w1.y, pa1);
      ETERM(a1.z + b1v.z, w1.z, pa1); ETERM(a1.w + b1v.w, w1.w, pa1);
    }
    {
      const int q = qb + 32;
      const float* ap = &CA[(7 + q - k) * 68 + (s << 3)];
      const float* bp = &CB[q * 68 + (s << 3)];
      float4 a0 = *(const float4*)ap, a1 = *(const float4*)(ap + 4);
      float4 b0 = *(const float4*)bp, b1v = *(const float4*)(bp + 4);
      ETERM(a0.x + b0.x, w0.x, pb0); ETERM(a0.y + b0.y, w0.y, pb0);
      ETERM(a0.z + b0.z, w0.z, pb0); ETERM(a0.w + b0.w, w0.w, pb0);
      ETERM(a1.x + b1v.x, w1.x, pb1); ETERM(a1.y + b1v.y, w1.y, pb1);
      ETERM(a1.z + b1v.z, w1.z, pb1); ETERM(a1.w + b1v.w, w1.w, pb1);
    }
  }
  const int ebase = blockIdx.x * NEDGE + (blockIdx.y << 9) + t;
  g_part[ebase] = (pa0 + pa1) + ws_all;
  g_part[ebase + 256] = (pb0 + pb1) + ws_all;
}

// K_tail: 32 blocks x 256 (R8-proven). Block b: edges [b*4096,(b+1)*4096) ->
// softplus + gold + 8 chunk recurrences -> 1 segment matrix. Last block (ticket)
// combines 32 segment matrices and writes out. 33 device fences total.
__global__ __launch_bounds__(256) void k_tail(const float* __restrict__ b2,
                                              float* __restrict__ out) {
  __shared__ float wf[64][64];   // [step][chunk_local*8 + k]
  __shared__ float red[256];
  __shared__ float m8[8][64];    // 8 chunk matrices
  __shared__ float l2m[4][64];   // final-combine wave partials
  __shared__ int s_tick;
  const int t = threadIdx.x;
  const int b = blockIdx.x;
  const float b2v = b2[0];
  float gold = 0.f;
#pragma unroll
  for (int it = 0; it < 4; ++it) {
    const int e4 = t + (it << 8);
    const int gidx = (b << 10) + e4;
    float4 s0 = *(const float4*)&g_part[gidx << 2];
    float4 s1 = *(const float4*)&g_part[NEDGE + (gidx << 2)];
    float4 s2 = *(const float4*)&g_part[2 * NEDGE + (gidx << 2)];
    float4 s3 = *(const float4*)&g_part[3 * NEDGE + (gidx << 2)];
    float d0 = s0.x + s1.x + s2.x + s3.x + b2v;
    float d1 = s0.y + s1.y + s2.y + s3.y + b2v;
    float d2 = s0.z + s1.z + s2.z + s3.z + b2v;
    float d3 = s0.w + s1.w + s2.w + s3.w + b2v;
    d0 = fmaxf(d0, 0.f) + log1pf(__expf(-fabsf(d0)));
    d1 = fmaxf(d1, 0.f) + log1pf(__expf(-fabsf(d1)));
    d2 = fmaxf(d2, 0.f) + log1pf(__expf(-fabsf(d2)));
    d3 = fmaxf(d3, 0.f) + log1pf(__expf(-fabsf(d3)));
    const int q = e4 << 2;
    const int cl = q >> 9, r = q & 511;
    const int s = r >> 3, kk = r & 7;
    *(float4*)&wf[s][(cl << 3) + kk] = make_float4(d0, d1, d2, d3);
    if ((t & 1) == 0) gold += d0;  // k==0 edges (gold path)
  }
  red[t] = gold;
  __syncthreads();
  if (b == 0 && t == 0) {
    // node i = s+1 has valid preds kk <= s only: poison invalid d with +1e30
    for (int s = 0; s < 7; ++s)
      for (int kk = s + 1; kk < 8; ++kk) wf[s][kk] = 1e30f;
  }
  for (int o = 128; o > 0; o >>= 1) {
    __syncthreads();
    if (t < o) red[t] += red[t + o];
  }
  __syncthreads();
  if (t == 0) atomicAdd(&g_gold, red[0]);
  if (t < 64) {  // wave 0: 8 chunk recurrences (8 lanes each)
    const int g = t >> 3, j = t & 7;
    float P[8];
#pragma unroll
    for (int kk = 0; kk < 8; ++kk) P[kk] = (kk == j) ? 0.f : NEG;
    for (int s = 0; s < 64; ++s) {
      const float* wp = &wf[s][g << 3];
      float4 wa = *(const float4*)wp;
      float4 wb = *(const float4*)(wp + 4);
      float nv = lse8(P[0] - wa.x, P[1] - wa.y, P[2] - wa.z, P[3] - wa.w,
                      P[4] - wb.x, P[5] - wb.y, P[6] - wb.z, P[7] - wb.w);
#pragma unroll
      for (int kk = 7; kk > 0; --kk) P[kk] = P[kk - 1];
      P[0] = nv;
    }
#pragma unroll
    for (int kk = 0; kk < 8; ++kk) m8[g][(kk << 3) + j] = P[kk];  // row-major
    // Combine 8 chunk mats -> segment mat (in-wave, DS ops in-order).
    const int i8 = (t >> 3) << 3;
    float R = m8[0][t];
#pragma unroll
    for (int g2 = 1; g2 < 8; ++g2) R = comb8(m8[g2][t], R, i8, j);
    g_mats[(b << 6) + t] = R;
  }
  __threadfence();
  __syncthreads();
  if (t == 0) s_tick = atomicAdd(&g_done, 1);
  __syncthreads();
  if (s_tick != 31) return;
  __threadfence();  // acquire: all 32 segment mats + gold adds visible

  // Final combine of 32 segment matrices. Wave w: segs 8w..8w+7.
  {
    const int l = t & 63, w = t >> 6;
    const int i8 = (l >> 3) << 3, j = l & 7;
    float G = g_mats[((w << 3) << 6) + l];
#pragma unroll
    for (int s2 = 1; s2 < 8; ++s2)
      G = comb8(g_mats[(((w << 3) + s2) << 6) + l], G, i8, j);
    l2m[w][l] = G;
    __syncthreads();
    if (t < 64) {
      float G2 = l2m[0][t];
#pragma unroll
      for (int w2 = 1; w2 < 4; ++w2) G2 = comb8(l2m[w2][t], G2, i8, j);
      if (t == 0) {
        out[0] = g_gold + G2;  // gold + (prod)[0][0]
        g_gold = 0.f;          // reset for next launch / graph replay
        g_done = 0;
      }
    }
  }
}

extern "C" void kernel_launch(void* const* d_in, const int* in_sizes, int n_in,
                              void* d_out, int out_size, void* d_ws, size_t ws_size,
                              hipStream_t stream) {
  const float* emb = (const float*)d_in[0];
  const float* W1 = (const float*)d_in[1];
  const float* b1 = (const float*)d_in[2];
  const float* W2 = (const float*)d_in[3];
  const float* b2 = (const float*)d_in[4];
  float* out = (float*)d_out;
  hipLaunchKernelGGL(k12_fused, dim3(4, 256), dim3(256), 0, stream, emb, W1, b1, W2);
  hipLaunchKernelGGL(k_tail, dim3(32), dim3(256), 0, stream, b2, out);
}